// Round 9
// baseline (170.005 us; speedup 1.0000x reference)
//
#include <hip/hip_runtime.h>
#include <hip/hip_bf16.h>

// Correlation loss via bf16 MFMA (r4 math), r9: latency-overlapped pipeline.
//   MFMA1: A = -2*m*msi~, B = m*msi~                      -> -2 m m g_m
//   MFMA2: A = m*{2h~,s_hi,s_lo,1,1,0}, B = m*{h~,1,1,s_hi,s_lo,0}
//          -> m m (2 g_h + s_p + s_q);   acc += |g[reg]|  (layout-agnostic)
// 400 worker blocks x 2 patches, double-buffered LDS: patch k+1's 35 global
// loads are issued before patch k's MFMA loop so their latency is hidden.
// Per-wave partials (no block reduction). Block 400 = reducer with s_sleep
// backoff polling (r8's hot 256-thread spin was a 19us regression).

#define PSZ  256
#define IMG  512
#define IMG2 (IMG * IMG)
#define XSTR 40          // ushorts per xs row = 80 B (16B-aligned)

typedef __attribute__((ext_vector_type(8))) short short8;
typedef __attribute__((ext_vector_type(4))) float float4v;

static __device__ __forceinline__ unsigned short f2bf(float v) {
    union { __hip_bfloat16 b; unsigned short u; } cv;
    cv.b = __float2bfloat16(v);
    return cv.u;
}
static __device__ __forceinline__ float bf2f(unsigned short u) {
    union { unsigned int u; float f; } cv;
    cv.u = ((unsigned int)u) << 16;
    return cv.f;
}

// issue the 35 per-pixel loads (kept in registers; no wait until first use)
static __device__ __forceinline__ void issue_loads(const float* __restrict__ msi,
                                                   const float* __restrict__ he,
                                                   int i0, int j0, int t, float* v) {
    const int r = t >> 4, c = t & 15;
    const float* mp = msi + (size_t)(i0 + r) * IMG + (j0 + c);
    const float* hp = he + (size_t)(i0 + r) * IMG + (j0 + c);
#pragma unroll
    for (int ch = 0; ch < 32; ++ch) v[ch] = mp[(size_t)ch * IMG2];
#pragma unroll
    for (int ch = 0; ch < 3; ++ch) v[32 + ch] = hp[(size_t)ch * IMG2];
}

// convert register pixel -> LDS fragments (r4/r5 math, unchanged)
static __device__ __forceinline__ void stage(const float* v, int t,
                                             unsigned short* xs,
                                             unsigned short* eA,
                                             unsigned short* eB) {
    const float h0 = v[32], h1 = v[33], h2 = v[34];
    const float mf = (h0 + h1 + h2 >= 0.05f) ? 1.f : 0.f;       // mask: exact fp32
    const unsigned short hb0 = f2bf(h0 * mf), hb1 = f2bf(h1 * mf), hb2 = f2bf(h2 * mf);
    const float hr0 = bf2f(hb0), hr1 = bf2f(hb1), hr2 = bf2f(hb2);
    const float sh = hr0 * hr0 + hr1 * hr1 + hr2 * hr2;

    float sm = 0.f;
#pragma unroll
    for (int g = 0; g < 4; ++g) {
        unsigned int pk[4];
#pragma unroll
        for (int k = 0; k < 4; ++k) {
            unsigned short lo = f2bf(v[g * 8 + 2 * k]     * mf);
            unsigned short hi = f2bf(v[g * 8 + 2 * k + 1] * mf);
            float fl = bf2f(lo), fh = bf2f(hi);
            sm = fmaf(fl, fl, sm);
            sm = fmaf(fh, fh, sm);
            pk[k] = (unsigned int)lo | ((unsigned int)hi << 16);
        }
        *(uint4*)&xs[t * XSTR + g * 8] = make_uint4(pk[0], pk[1], pk[2], pk[3]);
    }
    const float s = sm - sh;                 // masked already (m^2 = m)
    const unsigned short shi = f2bf(s);
    const unsigned short slo = f2bf(s - bf2f(shi));
    const unsigned short mb  = (mf != 0.f) ? (unsigned short)0x3F80 : (unsigned short)0;
    const unsigned short d0  = f2bf(2.f * hr0);   // exact: exponent+1
    const unsigned short d1  = f2bf(2.f * hr1);
    const unsigned short d2  = f2bf(2.f * hr2);
    *(uint4*)&eA[t * 8] = make_uint4(        // {2h0,2h1,2h2,s_hi,s_lo,m,m,0}
        (unsigned)d0 | ((unsigned)d1 << 16),
        (unsigned)d2 | ((unsigned)shi << 16),
        (unsigned)slo | ((unsigned)mb << 16),
        (unsigned)mb);
    *(uint4*)&eB[t * 8] = make_uint4(        // {h0,h1,h2,m,m,s_hi,s_lo,0}
        (unsigned)hb0 | ((unsigned)hb1 << 16),
        (unsigned)hb2 | ((unsigned)mb << 16),
        (unsigned)mb | ((unsigned)shi << 16),
        (unsigned)slo);
}

// MFMA main loop over one staged patch -> per-thread scalar sum
static __device__ __forceinline__ float mfma_patch(const unsigned short* xs,
                                                   const unsigned short* eA,
                                                   const unsigned short* eB,
                                                   int lane, int w) {
    const int mrow = lane & 15, quad = lane >> 4;
    const short8 zfrag = {0, 0, 0, 0, 0, 0, 0, 0};

    short8 Am[4], Ah[4];
#pragma unroll
    for (int ii = 0; ii < 4; ++ii) {           // x~ -> -2*x~: sign flip + exp+1
        const int ri = ((w << 2) + ii) * 16 + mrow;
        uint4 u = *(const uint4*)&xs[ri * XSTR + (quad << 3)];
        u.x = (u.x ^ 0x80008000u) + 0x00800080u;
        u.y = (u.y ^ 0x80008000u) + 0x00800080u;
        u.z = (u.z ^ 0x80008000u) + 0x00800080u;
        u.w = (u.w ^ 0x80008000u) + 0x00800080u;
        Am[ii] = *(const short8*)&u;
        Ah[ii] = (quad == 0) ? *(const short8*)&eA[ri << 3] : zfrag;
    }

    float acc[4] = {0.f, 0.f, 0.f, 0.f};
#pragma unroll 4
    for (int j = 0; j < 16; ++j) {
        const int cj = (j << 4) + mrow;
        short8 Bm = *(const short8*)&xs[cj * XSTR + (quad << 3)];
        short8 Bh = (quad == 0) ? *(const short8*)&eB[cj << 3] : zfrag;
        float4v g[4];
#pragma unroll
        for (int ii = 0; ii < 4; ++ii) {
            g[ii] = (float4v){0.f, 0.f, 0.f, 0.f};
            g[ii] = __builtin_amdgcn_mfma_f32_16x16x32_bf16(Ah[ii], Bh, g[ii], 0, 0, 0);
            g[ii] = __builtin_amdgcn_mfma_f32_16x16x32_bf16(Am[ii], Bm, g[ii], 0, 0, 0);
        }
#pragma unroll
        for (int ii = 0; ii < 4; ++ii) {
            acc[ii] += fabsf(g[ii][0]);
            acc[ii] += fabsf(g[ii][1]);
            acc[ii] += fabsf(g[ii][2]);
            acc[ii] += fabsf(g[ii][3]);
        }
    }
    return (acc[0] + acc[1]) + (acc[2] + acc[3]);
}

// wave-reduce + tagged release store of one per-wave partial
static __device__ __forceinline__ void emit(float a, int lane, float* slot) {
#pragma unroll
    for (int off = 32; off > 0; off >>= 1)
        a += __shfl_down(a, off, 64);
    if (lane == 0)          // tag: -(sum+1) <= -1, can't alias 0xAA poison bits
        __hip_atomic_store(slot, -(a + 1.0f), __ATOMIC_RELEASE,
                           __HIP_MEMORY_SCOPE_AGENT);
}

__global__ __launch_bounds__(256, 2)
void corr_loss_kernel(const float* __restrict__ msi,
                      const float* __restrict__ he,
                      const int* __restrict__ i_idx,
                      const int* __restrict__ j_idx,
                      float* __restrict__ partial,   // nslots = 2*nw*4
                      float* __restrict__ out,
                      int nw, float scale)
{
    __shared__ __align__(16) unsigned short xs0[PSZ * XSTR], xs1[PSZ * XSTR];
    __shared__ __align__(16) unsigned short eA0[PSZ * 8],   eA1[PSZ * 8];
    __shared__ __align__(16) unsigned short eB0[PSZ * 8],   eB1[PSZ * 8];
    __shared__ float red[4];

    const int b = blockIdx.x;
    const int t = threadIdx.x;
    const int lane = t & 63, w = t >> 6;

    // ---- reducer block ----
    if (b == nw) {
        const int nslots = nw * 8;             // 2 patches x 4 waves per worker
        float a = 0.f;
        for (int i = t; i < nslots; i += 256) {
            float v = __hip_atomic_load(&partial[i], __ATOMIC_ACQUIRE,
                                        __HIP_MEMORY_SCOPE_AGENT);
            for (;;) {
                union { float f; unsigned int u; } cv; cv.f = v;
                if (cv.u != 0xAAAAAAAAu && v < 0.0f) break;   // poison/0 rejected
                __builtin_amdgcn_s_sleep(8);                  // ~512 cyc backoff
                v = __hip_atomic_load(&partial[i], __ATOMIC_ACQUIRE,
                                      __HIP_MEMORY_SCOPE_AGENT);
            }
            a += (-v) - 1.0f;
        }
#pragma unroll
        for (int off = 32; off > 0; off >>= 1)
            a += __shfl_down(a, off, 64);
        if (lane == 0) red[w] = a;
        __syncthreads();
        if (t == 0)
            out[0] = ((red[0] + red[1]) + (red[2] + red[3])) * scale;
        return;
    }

    // ---- worker block: patches p0 = b, p1 = b + nw, pipelined ----
    const int i0 = i_idx[b],      j0 = j_idx[b];
    const int i1 = i_idx[b + nw], j1 = j_idx[b + nw];

    float v0[35];
    issue_loads(msi, he, i0, j0, t, v0);       // patch-0 loads in flight
    stage(v0, t, xs0, eA0, eB0);               // waits, converts -> LDS buf0
    __syncthreads();

    float v1[35];
    issue_loads(msi, he, i1, j1, t, v1);       // patch-1 loads fly under MFMA-0

    float a0 = mfma_patch(xs0, eA0, eB0, lane, w);
    emit(a0, lane, &partial[(b * 4 + w) * 2]);

    stage(v1, t, xs1, eA1, eB1);               // loads have landed by now
    __syncthreads();

    float a1 = mfma_patch(xs1, eA1, eB1, lane, w);
    emit(a1, lane, &partial[(b * 4 + w) * 2 + 1]);
}

extern "C" void kernel_launch(void* const* d_in, const int* in_sizes, int n_in,
                              void* d_out, int out_size, void* d_ws, size_t ws_size,
                              hipStream_t stream) {
    const float* msi   = (const float*)d_in[0];
    const float* he    = (const float*)d_in[1];
    const int*   i_idx = (const int*)d_in[2];
    const int*   j_idx = (const int*)d_in[3];
    const int    NB    = in_sizes[2];          // 800
    float*       out   = (float*)d_out;
    float*       part  = (float*)d_ws;         // 8*NW floats (poisoned 0xAA)

    const int NW = NB / 2;                     // 400 worker blocks x 2 patches
    const float scale = 1.0f / ((float)(PSZ * PSZ) * (float)(NB / 5));
    corr_loss_kernel<<<NW + 1, 256, 0, stream>>>(msi, he, i_idx, j_idx, part, out,
                                                 NW, scale);
}

// Round 10
// 111.718 us; speedup vs baseline: 1.5217x; 1.5217x over previous
//
#include <hip/hip_runtime.h>
#include <hip/hip_bf16.h>

// Correlation loss, fully folded into bf16 MFMA (r5 structure — empirical best).
// m_p m_q (dm - dh) = m_p m_q (s_p + s_q - 2 g_m + 2 g_h) from two chained
// 16x16x32 MFMAs per tile:
//   MFMA1: A = -2*m*msi~, B = m*msi~                     -> -2 m m g_m
//   MFMA2: A = m*{2h~,s_hi,s_lo,1,1,0}, B = m*{h~,1,1,s_hi,s_lo,0}
//          -> m m (2 g_h + s_p + s_q)
// Epilogue: acc += |g[reg]| (layout-agnostic). Partials -> d_ws (plain store),
// single-wave reduce kernel writes out[0].
// r8 (fused spin-reducer) and r9 (2-patch pipeline) both regressed badly —
// reverted. Staging scheme changes (LDS-DMA r6, record-image r7) were neutral
// or negative: the worker is per-block latency-bound, not instruction-bound.

#define PSZ  256
#define IMG  512
#define IMG2 (IMG * IMG)
#define XSTR 40          // ushorts per xs row = 80 B (16B-aligned)

typedef __attribute__((ext_vector_type(8))) short short8;
typedef __attribute__((ext_vector_type(4))) float float4v;

static __device__ __forceinline__ unsigned short f2bf(float v) {
    union { __hip_bfloat16 b; unsigned short u; } cv;
    cv.b = __float2bfloat16(v);
    return cv.u;
}
static __device__ __forceinline__ float bf2f(unsigned short u) {
    union { unsigned int u; float f; } cv;
    cv.u = ((unsigned int)u) << 16;
    return cv.f;
}

__global__ __launch_bounds__(256, 4)
void corr_loss_kernel(const float* __restrict__ msi,
                      const float* __restrict__ he,
                      const int* __restrict__ i_idx,
                      const int* __restrict__ j_idx,
                      float* __restrict__ partial)
{
    __shared__ __align__(16) unsigned short xs[PSZ * XSTR];  // m*bf16(msi) [p][k]
    __shared__ __align__(16) unsigned short eA[PSZ * 8];
    __shared__ __align__(16) unsigned short eB[PSZ * 8];
    __shared__ float red[4];

    const int b = blockIdx.x;
    const int t = threadIdx.x;
    const int i0 = i_idx[b], j0 = j_idx[b];

    // ---- stage column p = t: prefetch ALL loads, then convert ----
    {
        const int r = t >> 4, c = t & 15;
        const float* hp = he + (size_t)(i0 + r) * IMG + (j0 + c);
        const float* mp = msi + (size_t)(i0 + r) * IMG + (j0 + c);

        float h0 = hp[0], h1 = hp[IMG2], h2 = hp[2 * IMG2];
        float v[32];
#pragma unroll
        for (int ch = 0; ch < 32; ++ch) v[ch] = mp[(size_t)ch * IMG2];

        const float mf = (h0 + h1 + h2 >= 0.05f) ? 1.f : 0.f;   // mask: exact fp32
        const unsigned short hb0 = f2bf(h0 * mf), hb1 = f2bf(h1 * mf), hb2 = f2bf(h2 * mf);
        const float hr0 = bf2f(hb0), hr1 = bf2f(hb1), hr2 = bf2f(hb2);
        const float sh = hr0 * hr0 + hr1 * hr1 + hr2 * hr2;

        float sm = 0.f;
#pragma unroll
        for (int g = 0; g < 4; ++g) {
            unsigned int pk[4];
#pragma unroll
            for (int k = 0; k < 4; ++k) {
                unsigned short lo = f2bf(v[g * 8 + 2 * k]     * mf);
                unsigned short hi = f2bf(v[g * 8 + 2 * k + 1] * mf);
                float fl = bf2f(lo), fh = bf2f(hi);
                sm = fmaf(fl, fl, sm);
                sm = fmaf(fh, fh, sm);
                pk[k] = (unsigned int)lo | ((unsigned int)hi << 16);
            }
            *(uint4*)&xs[t * XSTR + g * 8] = make_uint4(pk[0], pk[1], pk[2], pk[3]);
        }
        const float s = sm - sh;                 // masked already (m^2 = m)
        const unsigned short shi = f2bf(s);
        const unsigned short slo = f2bf(s - bf2f(shi));
        const unsigned short mb  = (mf != 0.f) ? (unsigned short)0x3F80 : (unsigned short)0;
        const unsigned short d0  = f2bf(2.f * hr0);   // exact: exponent+1
        const unsigned short d1  = f2bf(2.f * hr1);
        const unsigned short d2  = f2bf(2.f * hr2);
        *(uint4*)&eA[t * 8] = make_uint4(          // {2h0,2h1,2h2,s_hi,s_lo,m,m,0}
            (unsigned)d0 | ((unsigned)d1 << 16),
            (unsigned)d2 | ((unsigned)shi << 16),
            (unsigned)slo | ((unsigned)mb << 16),
            (unsigned)mb);
        *(uint4*)&eB[t * 8] = make_uint4(          // {h0,h1,h2,m,m,s_hi,s_lo,0}
            (unsigned)hb0 | ((unsigned)hb1 << 16),
            (unsigned)hb2 | ((unsigned)mb << 16),
            (unsigned)mb | ((unsigned)shi << 16),
            (unsigned)slo);
    }
    __syncthreads();

    const int lane = t & 63, w = t >> 6;
    const int mrow = lane & 15, quad = lane >> 4;
    const short8 zfrag = {0, 0, 0, 0, 0, 0, 0, 0};

    // hoist A-frags; on-the-fly x~ -> -2*x~ (sign flip + exp+1, 0 <= x < 2)
    short8 Am[4], Ah[4];
#pragma unroll
    for (int ii = 0; ii < 4; ++ii) {
        const int ri = ((w << 2) + ii) * 16 + mrow;
        uint4 u = *(const uint4*)&xs[ri * XSTR + (quad << 3)];
        u.x = (u.x ^ 0x80008000u) + 0x00800080u;
        u.y = (u.y ^ 0x80008000u) + 0x00800080u;
        u.z = (u.z ^ 0x80008000u) + 0x00800080u;
        u.w = (u.w ^ 0x80008000u) + 0x00800080u;
        Am[ii] = *(const short8*)&u;
        Ah[ii] = (quad == 0) ? *(const short8*)&eA[ri << 3] : zfrag;
    }

    float acc[4] = {0.f, 0.f, 0.f, 0.f};
#pragma unroll 4
    for (int j = 0; j < 16; ++j) {
        const int cj = (j << 4) + mrow;
        short8 Bm = *(const short8*)&xs[cj * XSTR + (quad << 3)];
        short8 Bh = (quad == 0) ? *(const short8*)&eB[cj << 3] : zfrag;
        float4v g[4];
#pragma unroll
        for (int ii = 0; ii < 4; ++ii) {
            g[ii] = (float4v){0.f, 0.f, 0.f, 0.f};
            g[ii] = __builtin_amdgcn_mfma_f32_16x16x32_bf16(Ah[ii], Bh, g[ii], 0, 0, 0);
            g[ii] = __builtin_amdgcn_mfma_f32_16x16x32_bf16(Am[ii], Bm, g[ii], 0, 0, 0);
        }
#pragma unroll
        for (int ii = 0; ii < 4; ++ii) {
            acc[ii] += fabsf(g[ii][0]);
            acc[ii] += fabsf(g[ii][1]);
            acc[ii] += fabsf(g[ii][2]);
            acc[ii] += fabsf(g[ii][3]);
        }
    }
    float a = (acc[0] + acc[1]) + (acc[2] + acc[3]);

    // block reduction -> ONE plain store per block (no global atomics)
#pragma unroll
    for (int off = 32; off > 0; off >>= 1)
        a += __shfl_down(a, off, 64);
    if (lane == 0) red[w] = a;
    __syncthreads();
    if (t == 0)
        partial[b] = (red[0] + red[1]) + (red[2] + red[3]);
}

// single wave: no LDS, no barrier
__global__ __launch_bounds__(64)
void reduce_kernel(const float* __restrict__ partial, float* __restrict__ out,
                   int n, float scale)
{
    float a = 0.f;
    for (int i = threadIdx.x; i < n; i += 64) a += partial[i];
#pragma unroll
    for (int off = 32; off > 0; off >>= 1)
        a += __shfl_down(a, off, 64);
    if (threadIdx.x == 0) out[0] = a * scale;
}

extern "C" void kernel_launch(void* const* d_in, const int* in_sizes, int n_in,
                              void* d_out, int out_size, void* d_ws, size_t ws_size,
                              hipStream_t stream) {
    const float* msi   = (const float*)d_in[0];
    const float* he    = (const float*)d_in[1];
    const int*   i_idx = (const int*)d_in[2];
    const int*   j_idx = (const int*)d_in[3];
    const int    NB    = in_sizes[2];
    float*       out   = (float*)d_out;
    float*       part  = (float*)d_ws;        // NB floats of scratch

    const float scale = 1.0f / ((float)(PSZ * PSZ) * (float)(NB / 5));
    corr_loss_kernel<<<NB, 256, 0, stream>>>(msi, he, i_idx, j_idx, part);
    reduce_kernel<<<1, 64, 0, stream>>>(part, out, NB, scale);
}